// Round 4
// baseline (706.381 us; speedup 1.0000x reference)
//
#include <hip/hip_runtime.h>
#include <cstdint>
#include <cstddef>

#define N_ 4096
#define C_ 256

typedef _Float16 h8 __attribute__((ext_vector_type(8)));
typedef _Float16 h4 __attribute__((ext_vector_type(4)));
typedef float f4 __attribute__((ext_vector_type(4)));

// -------------------------------------- sq = sum x^2 ; split x -> f16 hi + lo
__global__ __launch_bounds__(256) void k_prep(const float* __restrict__ x,
                                              float* __restrict__ sq,
                                              _Float16* __restrict__ xh,
                                              _Float16* __restrict__ xl) {
  int wave = threadIdx.x >> 6, lane = threadIdx.x & 63;
  int row = blockIdx.x * 4 + wave;            // 0..16383
  size_t off = (size_t)row * C_ + lane * 4;
  float4 v = *(const float4*)(x + off);
  h4 hi; hi[0] = (_Float16)v.x; hi[1] = (_Float16)v.y;
         hi[2] = (_Float16)v.z; hi[3] = (_Float16)v.w;
  h4 lo; lo[0] = (_Float16)(v.x - (float)hi[0]); lo[1] = (_Float16)(v.y - (float)hi[1]);
         lo[2] = (_Float16)(v.z - (float)hi[2]); lo[3] = (_Float16)(v.w - (float)hi[3]);
  *(h4*)(xh + off) = hi;
  *(h4*)(xl + off) = lo;
  float s = v.x * v.x + v.y * v.y + v.z * v.z + v.w * v.w;
  s += __shfl_xor(s, 32); s += __shfl_xor(s, 16); s += __shfl_xor(s, 8);
  s += __shfl_xor(s, 4);  s += __shfl_xor(s, 2);  s += __shfl_xor(s, 1);
  if (lane == 0) sq[row] = s;
}

// ------------------- split W into f16 hi/lo, transposed to B-frag row layout
// wh[m][j*256 + k] = hi(W_m[k][j])   (j = out col, k = in dim)
__global__ __launch_bounds__(256) void k_wsplit(const float* __restrict__ Wq,
                                                const float* __restrict__ Wk,
                                                const float* __restrict__ Wv,
                                                _Float16* __restrict__ wh,
                                                _Float16* __restrict__ wl) {
  int g = blockIdx.x * 256 + threadIdx.x;     // 0..196607
  int m = g >> 16, e = g & 65535;
  int k = e >> 8, j = e & 255;                // read coalesced over j
  const float* W = (m == 0) ? Wq : ((m == 1) ? Wk : Wv);
  float v = W[k * 256 + j];
  _Float16 hi = (_Float16)v;
  _Float16 lo = (_Float16)(v - (float)hi);
  wh[m * 65536 + j * 256 + k] = hi;
  wl[m * 65536 + j * 256 + k] = lo;
}

// --------------------------- q/k/v projections via split-f16 MFMA (3 passes)
// grid = 3m x 128 row-blocks; block = 256 thr, wave owns 32 rows.
__global__ __launch_bounds__(256, 2) void k_proj(const _Float16* __restrict__ xh,
                                                 const _Float16* __restrict__ xl,
                                                 const _Float16* __restrict__ wh,
                                                 const _Float16* __restrict__ wl,
                                                 const float* __restrict__ bqp,
                                                 const float* __restrict__ bkp,
                                                 const float* __restrict__ bvp,
                                                 float* __restrict__ qf,
                                                 float* __restrict__ kf,
                                                 float* __restrict__ vf) {
  int tid = threadIdx.x;
  int m  = blockIdx.x / 128;
  int rb = blockIdx.x % 128;
  int wave = tid >> 6, lane = tid & 63, quad = lane >> 4, l16 = lane & 15;
  const float* bb = (m == 0) ? bqp : ((m == 1) ? bkp : bvp);
  float* dst      = (m == 0) ? qf  : ((m == 1) ? kf  : vf);
  int row0 = rb * 128 + wave * 32;

  h8 Ah[2][8], Al[2][8];
#pragma unroll
  for (int rt = 0; rt < 2; rt++)
#pragma unroll
    for (int kc = 0; kc < 8; kc++) {
      size_t off = (size_t)(row0 + rt * 16 + l16) * C_ + kc * 32 + quad * 8;
      Ah[rt][kc] = *(const h8*)(xh + off);
      Al[rt][kc] = *(const h8*)(xl + off);
    }
  const _Float16* whm = wh + (size_t)m * 65536;
  const _Float16* wlm = wl + (size_t)m * 65536;

#pragma unroll 1
  for (int cp = 0; cp < 2; cp++) {
    f4 acc[2][8];
#pragma unroll
    for (int rt = 0; rt < 2; rt++)
#pragma unroll
      for (int ct = 0; ct < 8; ct++) acc[rt][ct] = f4{0.f, 0.f, 0.f, 0.f};
#pragma unroll
    for (int kc = 0; kc < 8; kc++) {
#pragma unroll
      for (int ct = 0; ct < 8; ct++) {
        int col = cp * 128 + ct * 16 + l16;
        h8 bh = *(const h8*)(whm + (size_t)col * 256 + kc * 32 + quad * 8);
        h8 bl = *(const h8*)(wlm + (size_t)col * 256 + kc * 32 + quad * 8);
#pragma unroll
        for (int rt = 0; rt < 2; rt++) {
          acc[rt][ct] = __builtin_amdgcn_mfma_f32_16x16x32_f16(Ah[rt][kc], bh, acc[rt][ct], 0, 0, 0);
          acc[rt][ct] = __builtin_amdgcn_mfma_f32_16x16x32_f16(Ah[rt][kc], bl, acc[rt][ct], 0, 0, 0);
          acc[rt][ct] = __builtin_amdgcn_mfma_f32_16x16x32_f16(Al[rt][kc], bh, acc[rt][ct], 0, 0, 0);
        }
      }
    }
#pragma unroll
    for (int rt = 0; rt < 2; rt++)
#pragma unroll
      for (int ct = 0; ct < 8; ct++) {
        int col = cp * 128 + ct * 16 + l16;
        float bias = bb[col];
#pragma unroll
        for (int i = 0; i < 4; i++) {
          int r = row0 + rt * 16 + quad * 4 + i;
          dst[(size_t)r * C_ + col] = acc[rt][ct][i] + bias;
        }
      }
  }
}

// ------------- cooperative split-f16 MFMA distance GEMM + parallel top-16
// block: 128 targets x 1024 sources (chunks of 32), 4 waves.
// bid = ((b*32 + tile)*4 + s4); grid 512 x 256 thr.
__global__ __launch_bounds__(256, 2) void k_knn(const _Float16* __restrict__ xh,
                                                const _Float16* __restrict__ xl,
                                                const float* __restrict__ sq,
                                                float* __restrict__ pd,
                                                int* __restrict__ pi) {
  __shared__ _Float16 Bh[32 * 264];           // 32 src rows x K=256, pad 8
  __shared__ _Float16 Bl[32 * 264];
  __shared__ float sc[32 * 137];              // col-major d2: sc[c*137 + r]
  __shared__ float kd[128 * 17];
  __shared__ int   ki[128 * 17];
  __shared__ float sqS[32];

  int tid = threadIdx.x;
  int wave = tid >> 6, lane = tid & 63, quad = lane >> 4, l16 = lane & 15;
  int bid = blockIdx.x;
  int s4   = bid & 3;
  int tile = (bid >> 2) & 31;
  int b    = bid >> 7;
  int bN = b * N_, n0 = tile * 128, src0g = s4 * 1024;

  {
    int r = tid >> 1, p0 = (tid & 1) * 8;
#pragma unroll
    for (int p = 0; p < 8; p++) { kd[r * 17 + p0 + p] = 1e38f; ki[r * 17 + p0 + p] = 0; }
  }

  // A-frags: wave's 32 target rows, full K, hi+lo (resident all kernel)
  h8 Ah[2][8], Al[2][8];
  int tb = bN + n0 + wave * 32;
#pragma unroll
  for (int rt = 0; rt < 2; rt++)
#pragma unroll
    for (int kc = 0; kc < 8; kc++) {
      size_t off = (size_t)(tb + rt * 16 + l16) * C_ + kc * 32 + quad * 8;
      Ah[rt][kc] = *(const h8*)(xh + off);
      Al[rt][kc] = *(const h8*)(xl + off);
    }
  float sqT[2][4];
#pragma unroll
  for (int rt = 0; rt < 2; rt++)
#pragma unroll
    for (int i = 0; i < 4; i++)
      sqT[rt][i] = sq[tb + rt * 16 + quad * 4 + i];

  float thr = 1e38f;                           // merge threshold (tid<128 only)

#pragma unroll 1
  for (int ch = 0; ch < 32; ch++) {
    int src0 = src0g + ch * 32;
    __syncthreads();                           // prev merge (sc) + B reads done
    // stage B chunk: 32 rows x 256 f16, hi+lo; coalesced 16B, padded LDS
#pragma unroll
    for (int i = 0; i < 4; i++) {
      int seg = tid + i * 256;                 // 0..1023
      int row = seg >> 5, o = seg & 31;
      size_t go = (size_t)(bN + src0 + row) * C_ + o * 8;
      *(h8*)(&Bh[row * 264 + o * 8]) = *(const h8*)(xh + go);
      *(h8*)(&Bl[row * 264 + o * 8]) = *(const h8*)(xl + go);
    }
    if (tid < 32) sqS[tid] = sq[bN + src0 + tid];
    __syncthreads();

    f4 acc[2][2];
#pragma unroll
    for (int rt = 0; rt < 2; rt++)
#pragma unroll
      for (int ct = 0; ct < 2; ct++) acc[rt][ct] = f4{0.f, 0.f, 0.f, 0.f};
#pragma unroll
    for (int kc = 0; kc < 8; kc++) {
      h8 bh[2], bl[2];
#pragma unroll
      for (int ct = 0; ct < 2; ct++) {
        bh[ct] = *(const h8*)(&Bh[(ct * 16 + l16) * 264 + kc * 32 + quad * 8]);
        bl[ct] = *(const h8*)(&Bl[(ct * 16 + l16) * 264 + kc * 32 + quad * 8]);
      }
#pragma unroll
      for (int rt = 0; rt < 2; rt++)
#pragma unroll
        for (int ct = 0; ct < 2; ct++) {
          acc[rt][ct] = __builtin_amdgcn_mfma_f32_16x16x32_f16(Ah[rt][kc], bh[ct], acc[rt][ct], 0, 0, 0);
          acc[rt][ct] = __builtin_amdgcn_mfma_f32_16x16x32_f16(Ah[rt][kc], bl[ct], acc[rt][ct], 0, 0, 0);
          acc[rt][ct] = __builtin_amdgcn_mfma_f32_16x16x32_f16(Al[rt][kc], bh[ct], acc[rt][ct], 0, 0, 0);
        }
    }
    // d2 -> sc (col-major, conflict-free), with self-mask
    float sqSr[2];
#pragma unroll
    for (int ct = 0; ct < 2; ct++) sqSr[ct] = sqS[ct * 16 + l16];
#pragma unroll
    for (int rt = 0; rt < 2; rt++)
#pragma unroll
      for (int ct = 0; ct < 2; ct++) {
        int c = ct * 16 + l16;
#pragma unroll
        for (int i = 0; i < 4; i++) {
          int r = wave * 32 + rt * 16 + quad * 4 + i;
          float d2 = sqT[rt][i] + sqSr[ct] - 2.0f * acc[rt][ct][i];
          if (n0 + r == src0 + c) d2 = 1e38f;
          sc[c * 137 + r] = d2;
        }
      }
    __syncthreads();
    // parallel merge: threads 0..127, one target row each
    if (tid < 128) {
      int r = tid;
#pragma unroll 1
      for (int c = 0; c < 32; c++) {
        float d = sc[c * 137 + r];
        if (d < thr) {
          int p = 15;
          while (p > 0 && kd[r * 17 + p - 1] > d) {
            kd[r * 17 + p] = kd[r * 17 + p - 1];
            ki[r * 17 + p] = ki[r * 17 + p - 1];
            p--;
          }
          kd[r * 17 + p] = d;
          ki[r * 17 + p] = src0 + c;
          thr = kd[r * 17 + 15];
        }
      }
    }
  }
  __syncthreads();
  if (tid < 128) {
#pragma unroll
    for (int p = 0; p < 16; p++) {
      size_t e = ((size_t)bid * 128 + tid) * 16 + p;
      pd[e] = kd[tid * 17 + p];
      pi[e] = ki[tid * 17 + p];
    }
  }
}

// ------------------------------------- merge 4 partial sorted lists -> top-16
__global__ __launch_bounds__(256) void k_kmerge(const float* __restrict__ pd,
                                                const int* __restrict__ pi,
                                                int* __restrict__ idxo) {
  int g = blockIdx.x * 256 + threadIdx.x;      // 0..16383
  int b = g >> 12, n = g & 4095;
  int tile = n >> 7, r = n & 127;
  int base[4], p[4];
  float hd[4];
#pragma unroll
  for (int s = 0; s < 4; s++) {
    base[s] = (((b * 32 + tile) * 4 + s) * 128 + r) * 16;
    p[s] = 0;
    hd[s] = pd[base[s]];
  }
#pragma unroll
  for (int k = 0; k < 16; k++) {
    int bs = 0; float bd = hd[0];
#pragma unroll
    for (int s = 1; s < 4; s++) if (hd[s] < bd) { bd = hd[s]; bs = s; }
    idxo[(size_t)g * 16 + k] = pi[base[bs] + p[bs]];
    p[bs]++;
    hd[bs] = (p[bs] < 16) ? pd[base[bs] + p[bs]] : 1e38f;
  }
}

// -------------------------------------------- gather + attention (wave/node)
__global__ __launch_bounds__(256) void k_attn(const float* __restrict__ qf,
                                              const float* __restrict__ kf,
                                              const float* __restrict__ vf,
                                              const int* __restrict__ idxv,
                                              float* __restrict__ out) {
  int wave = threadIdx.x >> 6, lane = threadIdx.x & 63;
  int g = blockIdx.x * 4 + wave;               // node 0..16383
  int bN = (g >> 12) << 12;
  float4 q4 = *(const float4*)(qf + (size_t)g * C_ + lane * 4);
  int my = idxv[(size_t)g * 16 + (lane & 15)];
  const float scale = 0.17677669529663687f;    // 1/sqrt(32)

  float s[16];
  float4 vv[16];
#pragma unroll
  for (int j = 0; j < 16; j++) {
    int nb = __shfl(my, j);
    size_t base = (size_t)(bN + nb) * C_ + lane * 4;
    float4 k4 = *(const float4*)(kf + base);
    vv[j] = *(const float4*)(vf + base);
    float p = k4.x * q4.x + k4.y * q4.y + k4.z * q4.z + k4.w * q4.w;
    p += __shfl_xor(p, 1); p += __shfl_xor(p, 2); p += __shfl_xor(p, 4);
    s[j] = p * scale;
  }
  float mx = s[0];
#pragma unroll
  for (int j = 1; j < 16; j++) mx = fmaxf(mx, s[j]);
  float den = 0.f;
#pragma unroll
  for (int j = 0; j < 16; j++) { s[j] = __expf(s[j] - mx); den += s[j]; }
  float inv = 1.0f / den;
  float4 o; o.x = 0.f; o.y = 0.f; o.z = 0.f; o.w = 0.f;
#pragma unroll
  for (int j = 0; j < 16; j++) {
    float w = s[j] * inv;
    o.x = fmaf(w, vv[j].x, o.x); o.y = fmaf(w, vv[j].y, o.y);
    o.z = fmaf(w, vv[j].z, o.z); o.w = fmaf(w, vv[j].w, o.w);
  }
  *(float4*)(out + (size_t)g * C_ + lane * 4) = o;
}

extern "C" void kernel_launch(void* const* d_in, const int* in_sizes, int n_in,
                              void* d_out, int out_size, void* d_ws, size_t ws_size,
                              hipStream_t stream) {
  const float* x  = (const float*)d_in[0];
  const float* Wq = (const float*)d_in[1];
  const float* bq = (const float*)d_in[2];
  const float* Wk = (const float*)d_in[3];
  const float* bk = (const float*)d_in[4];
  const float* Wv = (const float*)d_in[5];
  const float* bv = (const float*)d_in[6];
  float* out = (float*)d_out;

  char* ws = (char*)d_ws;
  float*     sqp  = (float*)(ws + 0);                //  64 KB
  _Float16*  xh   = (_Float16*)(ws + 65536);         //   8 MB
  _Float16*  xl   = (_Float16*)(ws + 8454144);       //   8 MB
  float*     qf   = (float*)(ws + 16842752);         //  16 MB
  float*     kf   = (float*)(ws + 33619968);         //  16 MB
  float*     vf   = (float*)(ws + 50397184);         //  16 MB
  float*     pd   = (float*)(ws + 67174400);         //   4 MB
  int*       pi   = (int*)  (ws + 71368704);         //   4 MB
  int*       idxb = (int*)  (ws + 75563008);         //   1 MB
  _Float16*  whf  = (_Float16*)(ws + 76611584);      // 384 KB
  _Float16*  wlf  = (_Float16*)(ws + 77004800);      // 384 KB (total ~74 MB)

  k_prep  <<<4096, 256, 0, stream>>>(x, sqp, xh, xl);
  k_wsplit<<<768,  256, 0, stream>>>(Wq, Wk, Wv, whf, wlf);
  k_proj  <<<384,  256, 0, stream>>>(xh, xl, whf, wlf, bq, bk, bv, qf, kf, vf);
  k_knn   <<<512,  256, 0, stream>>>(xh, xl, sqp, pd, pi);
  k_kmerge<<<64,   256, 0, stream>>>(pd, pi, idxb);
  k_attn  <<<4096, 256, 0, stream>>>(qf, kf, vf, idxb, out);
}

// Round 6
// 348.883 us; speedup vs baseline: 2.0247x; 2.0247x over previous
//
#include <hip/hip_runtime.h>
#include <cstdint>
#include <cstddef>

#define N_ 4096
#define C_ 256

typedef _Float16 h8 __attribute__((ext_vector_type(8)));
typedef _Float16 h4 __attribute__((ext_vector_type(4)));
typedef float f4 __attribute__((ext_vector_type(4)));

__device__ __forceinline__ void gl2lds16(const void* g, void* l) {
  __builtin_amdgcn_global_load_lds((const __attribute__((address_space(1))) void*)g,
                                   (__attribute__((address_space(3))) void*)l, 16, 0, 0);
}

// -------------------------------------- sq = sum x^2 ; split x -> f16 hi + lo
__global__ __launch_bounds__(256) void k_prep(const float* __restrict__ x,
                                              float* __restrict__ sq,
                                              _Float16* __restrict__ xh,
                                              _Float16* __restrict__ xl) {
  int wave = threadIdx.x >> 6, lane = threadIdx.x & 63;
  int row = blockIdx.x * 4 + wave;            // 0..16383
  size_t off = (size_t)row * C_ + lane * 4;
  float4 v = *(const float4*)(x + off);
  h4 hi; hi[0] = (_Float16)v.x; hi[1] = (_Float16)v.y;
         hi[2] = (_Float16)v.z; hi[3] = (_Float16)v.w;
  h4 lo; lo[0] = (_Float16)(v.x - (float)hi[0]); lo[1] = (_Float16)(v.y - (float)hi[1]);
         lo[2] = (_Float16)(v.z - (float)hi[2]); lo[3] = (_Float16)(v.w - (float)hi[3]);
  *(h4*)(xh + off) = hi;
  *(h4*)(xl + off) = lo;
  float s = v.x * v.x + v.y * v.y + v.z * v.z + v.w * v.w;
  s += __shfl_xor(s, 32); s += __shfl_xor(s, 16); s += __shfl_xor(s, 8);
  s += __shfl_xor(s, 4);  s += __shfl_xor(s, 2);  s += __shfl_xor(s, 1);
  if (lane == 0) sq[row] = s;
}

// ------------------- split W into f16 hi/lo, transposed to B-frag row layout
__global__ __launch_bounds__(256) void k_wsplit(const float* __restrict__ Wq,
                                                const float* __restrict__ Wk,
                                                const float* __restrict__ Wv,
                                                _Float16* __restrict__ wh,
                                                _Float16* __restrict__ wl) {
  int g = blockIdx.x * 256 + threadIdx.x;     // 0..196607
  int m = g >> 16, e = g & 65535;
  int k = e >> 8, j = e & 255;
  const float* W = (m == 0) ? Wq : ((m == 1) ? Wk : Wv);
  float v = W[k * 256 + j];
  _Float16 hi = (_Float16)v;
  _Float16 lo = (_Float16)(v - (float)hi);
  wh[m * 65536 + j * 256 + k] = hi;
  wl[m * 65536 + j * 256 + k] = lo;
}

// --------------------------- q/k/v projections via split-f16 MFMA (3 passes)
__global__ __launch_bounds__(256, 2) void k_proj(const _Float16* __restrict__ xh,
                                                 const _Float16* __restrict__ xl,
                                                 const _Float16* __restrict__ wh,
                                                 const _Float16* __restrict__ wl,
                                                 const float* __restrict__ bqp,
                                                 const float* __restrict__ bkp,
                                                 const float* __restrict__ bvp,
                                                 float* __restrict__ qf,
                                                 float* __restrict__ kf,
                                                 float* __restrict__ vf) {
  int tid = threadIdx.x;
  int m  = blockIdx.x / 128;
  int rb = blockIdx.x % 128;
  int wave = tid >> 6, lane = tid & 63, quad = lane >> 4, l16 = lane & 15;
  const float* bb = (m == 0) ? bqp : ((m == 1) ? bkp : bvp);
  float* dst      = (m == 0) ? qf  : ((m == 1) ? kf  : vf);
  int row0 = rb * 128 + wave * 32;

  h8 Ah[2][8], Al[2][8];
#pragma unroll
  for (int rt = 0; rt < 2; rt++)
#pragma unroll
    for (int kc = 0; kc < 8; kc++) {
      size_t off = (size_t)(row0 + rt * 16 + l16) * C_ + kc * 32 + quad * 8;
      Ah[rt][kc] = *(const h8*)(xh + off);
      Al[rt][kc] = *(const h8*)(xl + off);
    }
  const _Float16* whm = wh + (size_t)m * 65536;
  const _Float16* wlm = wl + (size_t)m * 65536;

#pragma unroll 1
  for (int cp = 0; cp < 2; cp++) {
    f4 acc[2][8];
#pragma unroll
    for (int rt = 0; rt < 2; rt++)
#pragma unroll
      for (int ct = 0; ct < 8; ct++) acc[rt][ct] = f4{0.f, 0.f, 0.f, 0.f};
#pragma unroll
    for (int kc = 0; kc < 8; kc++) {
#pragma unroll
      for (int ct = 0; ct < 8; ct++) {
        int col = cp * 128 + ct * 16 + l16;
        h8 bh = *(const h8*)(whm + (size_t)col * 256 + kc * 32 + quad * 8);
        h8 bl = *(const h8*)(wlm + (size_t)col * 256 + kc * 32 + quad * 8);
#pragma unroll
        for (int rt = 0; rt < 2; rt++) {
          acc[rt][ct] = __builtin_amdgcn_mfma_f32_16x16x32_f16(Ah[rt][kc], bh, acc[rt][ct], 0, 0, 0);
          acc[rt][ct] = __builtin_amdgcn_mfma_f32_16x16x32_f16(Ah[rt][kc], bl, acc[rt][ct], 0, 0, 0);
          acc[rt][ct] = __builtin_amdgcn_mfma_f32_16x16x32_f16(Al[rt][kc], bh, acc[rt][ct], 0, 0, 0);
        }
      }
    }
#pragma unroll
    for (int rt = 0; rt < 2; rt++)
#pragma unroll
      for (int ct = 0; ct < 8; ct++) {
        int col = cp * 128 + ct * 16 + l16;
        float bias = bb[col];
#pragma unroll
        for (int i = 0; i < 4; i++) {
          int r = row0 + rt * 16 + quad * 4 + i;
          dst[(size_t)r * C_ + col] = acc[rt][ct][i] + bias;
        }
      }
  }
}

// ---- split-f16 MFMA distance GEMM + branchless packed-f64 register top-16
// block: 128 targets x 1024 srcs (32-chunks), 4 waves, glds staging.
// bid = ((b*32 + tile)*4 + s4); grid 512 x 256.
__global__ __launch_bounds__(256, 2) void k_knn(const _Float16* __restrict__ xh,
                                                const _Float16* __restrict__ xl,
                                                const float* __restrict__ sq,
                                                double* __restrict__ pd) {
  __shared__ __align__(16) _Float16 Bh[16 * 528]; // 16 segs x (2 rows x 256 + 8 pad)
  __shared__ __align__(16) _Float16 Bl[16 * 528];
  __shared__ __align__(16) float sc[128 * 36];    // row-major d2, stride 36
  __shared__ float sqS[32];

  int tid = threadIdx.x;
  int wave = tid >> 6, lane = tid & 63, quad = lane >> 4, l16 = lane & 15;
  int bid = blockIdx.x;
  int s4 = bid & 3, tile = (bid >> 2) & 31, b = bid >> 7;
  int bN = b * N_, n0 = tile * 128, src0g = s4 * 1024;

  // A-frags: wave's 32 target rows, full K, hi+lo, resident
  h8 Ah[2][8], Al[2][8];
  int tb = bN + n0 + wave * 32;
#pragma unroll
  for (int rt = 0; rt < 2; rt++)
#pragma unroll
    for (int kc = 0; kc < 8; kc++) {
      size_t off = (size_t)(tb + rt * 16 + l16) * C_ + kc * 32 + quad * 8;
      Ah[rt][kc] = *(const h8*)(xh + off);
      Al[rt][kc] = *(const h8*)(xl + off);
    }
  float sqT[2][4];
#pragma unroll
  for (int rt = 0; rt < 2; rt++)
#pragma unroll
    for (int i = 0; i < 4; i++)
      sqT[rt][i] = sq[tb + rt * 16 + quad * 4 + i];

  double karr[16];
#pragma unroll
  for (int p = 0; p < 16; p++) karr[p] = 1e300;
  int rowo = tid & 127, half = tid >> 7;

  // prologue: stage chunk 0. seg = 2 src rows = 1KB; lane i -> bytes [16i,16i+16)
  {
    const _Float16* gh = xh + (size_t)(bN + src0g) * C_ + lane * 8;
    const _Float16* gl = xl + (size_t)(bN + src0g) * C_ + lane * 8;
#pragma unroll
    for (int k = 0; k < 4; k++) {
      int seg = wave * 4 + k;
      gl2lds16(gh + seg * 512, &Bh[seg * 528]);
      gl2lds16(gl + seg * 512, &Bl[seg * 528]);
    }
    if (tid < 32) sqS[tid] = sq[bN + src0g + tid];
  }

  int hb0 = ((l16 >> 1) * 528) + ((l16 & 1) * 256) + quad * 8;          // ct=0 row
  int hb1 = (((16 + l16) >> 1) * 528) + ((l16 & 1) * 256) + quad * 8;   // ct=1 row

#pragma unroll 1
  for (int ch = 0; ch < 32; ch++) {
    int src0 = src0g + ch * 32;
    __syncthreads();                       // staged B(ch) + sqS(ch) visible

    f4 acc[2][2];
#pragma unroll
    for (int rt = 0; rt < 2; rt++)
#pragma unroll
      for (int ct = 0; ct < 2; ct++) acc[rt][ct] = f4{0.f, 0.f, 0.f, 0.f};
#pragma unroll
    for (int kc = 0; kc < 8; kc++) {
      h8 bh0 = *(const h8*)(&Bh[hb0 + kc * 32]);
      h8 bh1 = *(const h8*)(&Bh[hb1 + kc * 32]);
      h8 bl0 = *(const h8*)(&Bl[hb0 + kc * 32]);
      h8 bl1 = *(const h8*)(&Bl[hb1 + kc * 32]);
#pragma unroll
      for (int rt = 0; rt < 2; rt++) {
        acc[rt][0] = __builtin_amdgcn_mfma_f32_16x16x32_f16(Ah[rt][kc], bh0, acc[rt][0], 0, 0, 0);
        acc[rt][0] = __builtin_amdgcn_mfma_f32_16x16x32_f16(Ah[rt][kc], bl0, acc[rt][0], 0, 0, 0);
        acc[rt][0] = __builtin_amdgcn_mfma_f32_16x16x32_f16(Al[rt][kc], bh0, acc[rt][0], 0, 0, 0);
        acc[rt][1] = __builtin_amdgcn_mfma_f32_16x16x32_f16(Ah[rt][kc], bh1, acc[rt][1], 0, 0, 0);
        acc[rt][1] = __builtin_amdgcn_mfma_f32_16x16x32_f16(Ah[rt][kc], bl1, acc[rt][1], 0, 0, 0);
        acc[rt][1] = __builtin_amdgcn_mfma_f32_16x16x32_f16(Al[rt][kc], bh1, acc[rt][1], 0, 0, 0);
      }
    }
    // d2 -> sc row-major (stride 36; 2-way banks max), self-masked
    float sqSr[2] = {sqS[l16], sqS[16 + l16]};
#pragma unroll
    for (int rt = 0; rt < 2; rt++)
#pragma unroll
      for (int ct = 0; ct < 2; ct++) {
        int c = ct * 16 + l16;
#pragma unroll
        for (int i = 0; i < 4; i++) {
          int r = wave * 32 + rt * 16 + quad * 4 + i;
          float d2 = sqT[rt][i] + sqSr[ct] - 2.0f * acc[rt][ct][i];
          if (n0 + r == src0 + c) d2 = 1e38f;
          sc[r * 36 + c] = d2;
        }
      }
    __syncthreads();                       // sc ready; all B(ch) reads done

    if (ch < 31) {                         // async-stage chunk ch+1
      int srcn = src0 + 32;
      const _Float16* gh = xh + (size_t)(bN + srcn) * C_ + lane * 8;
      const _Float16* gl = xl + (size_t)(bN + srcn) * C_ + lane * 8;
#pragma unroll
      for (int k = 0; k < 4; k++) {
        int seg = wave * 4 + k;
        gl2lds16(gh + seg * 512, &Bh[seg * 528]);
        gl2lds16(gl + seg * 512, &Bl[seg * 528]);
      }
      if (tid < 32) sqS[tid] = sq[bN + srcn + tid];
    }

    // merge: 16 candidates (my half-row); gated branchless f64 sorted insert
    float dv[16];
#pragma unroll
    for (int k4 = 0; k4 < 4; k4++)
      *(float4*)&dv[k4 * 4] = *(const float4*)(&sc[rowo * 36 + half * 16 + k4 * 4]);
#pragma unroll
    for (int j = 0; j < 16; j++) {
      double key = (double)dv[j];
      key = __longlong_as_double(__double_as_longlong(key) |
                                 (unsigned)(src0 + half * 16 + j));
      if (key < karr[15]) {                // register-only; exec-mask divergence ok
#pragma unroll
        for (int p = 15; p >= 1; p--)
          karr[p] = fmin(fmax(key, karr[p - 1]), karr[p]);
        karr[0] = fmin(karr[0], key);
      }
    }
  }

  // combine half-streams: thread t>=128 publishes, t<128 inserts partner's 16
  __syncthreads();
  double* scd = (double*)sc;
  if (tid >= 128) {
#pragma unroll
    for (int p = 0; p < 16; p++) scd[(tid - 128) * 17 + p] = karr[p];
  }
  __syncthreads();
  if (tid < 128) {
#pragma unroll
    for (int j = 0; j < 16; j++) {
      double key = scd[tid * 17 + j];
      if (key < karr[15]) {
#pragma unroll
        for (int p = 15; p >= 1; p--)
          karr[p] = fmin(fmax(key, karr[p - 1]), karr[p]);
        karr[0] = fmin(karr[0], key);
      }
    }
#pragma unroll
    for (int p = 0; p < 16; p++)
      pd[((size_t)bid * 128 + tid) * 16 + p] = karr[p];
  }
}

// --------------------- merge 4 partial sorted packed lists -> top-16 indices
__global__ __launch_bounds__(256) void k_kmerge(const double* __restrict__ pd,
                                                int* __restrict__ idxo) {
  int g = blockIdx.x * 256 + threadIdx.x;      // 0..16383
  int b = g >> 12, n = g & 4095;
  int tile = n >> 7, r = n & 127;
  size_t base[4]; int p[4]; double hd[4];
#pragma unroll
  for (int s = 0; s < 4; s++) {
    base[s] = (size_t)(((b * 32 + tile) * 4 + s) * 128 + r) * 16;
    p[s] = 0;
    hd[s] = pd[base[s]];
  }
#pragma unroll
  for (int k = 0; k < 16; k++) {
    int bs = 0; double bd = hd[0];
#pragma unroll
    for (int s = 1; s < 4; s++) if (hd[s] < bd) { bd = hd[s]; bs = s; }
    idxo[(size_t)g * 16 + k] = (int)(__double_as_longlong(bd) & 0xFFF);
    p[bs]++;
    hd[bs] = (p[bs] < 16) ? pd[base[bs] + p[bs]] : 1e301;
  }
}

// -------------------------------------------- gather + attention (wave/node)
__global__ __launch_bounds__(256) void k_attn(const float* __restrict__ qf,
                                              const float* __restrict__ kf,
                                              const float* __restrict__ vf,
                                              const int* __restrict__ idxv,
                                              float* __restrict__ out) {
  int wave = threadIdx.x >> 6, lane = threadIdx.x & 63;
  int g = blockIdx.x * 4 + wave;               // node 0..16383
  int bN = (g >> 12) << 12;
  float4 q4 = *(const float4*)(qf + (size_t)g * C_ + lane * 4);
  int my = idxv[(size_t)g * 16 + (lane & 15)];
  const float scale = 0.17677669529663687f;    // 1/sqrt(32)

  float s[16];
  float4 vv[16];
#pragma unroll
  for (int j = 0; j < 16; j++) {
    int nb = __shfl(my, j);
    size_t base = (size_t)(bN + nb) * C_ + lane * 4;
    float4 k4 = *(const float4*)(kf + base);
    vv[j] = *(const float4*)(vf + base);
    float p = k4.x * q4.x + k4.y * q4.y + k4.z * q4.z + k4.w * q4.w;
    p += __shfl_xor(p, 1); p += __shfl_xor(p, 2); p += __shfl_xor(p, 4);
    s[j] = p * scale;
  }
  float mx = s[0];
#pragma unroll
  for (int j = 1; j < 16; j++) mx = fmaxf(mx, s[j]);
  float den = 0.f;
#pragma unroll
  for (int j = 0; j < 16; j++) { s[j] = __expf(s[j] - mx); den += s[j]; }
  float inv = 1.0f / den;
  float4 o; o.x = 0.f; o.y = 0.f; o.z = 0.f; o.w = 0.f;
#pragma unroll
  for (int j = 0; j < 16; j++) {
    float w = s[j] * inv;
    o.x = fmaf(w, vv[j].x, o.x); o.y = fmaf(w, vv[j].y, o.y);
    o.z = fmaf(w, vv[j].z, o.z); o.w = fmaf(w, vv[j].w, o.w);
  }
  *(float4*)(out + (size_t)g * C_ + lane * 4) = o;
}

extern "C" void kernel_launch(void* const* d_in, const int* in_sizes, int n_in,
                              void* d_out, int out_size, void* d_ws, size_t ws_size,
                              hipStream_t stream) {
  const float* x  = (const float*)d_in[0];
  const float* Wq = (const float*)d_in[1];
  const float* bq = (const float*)d_in[2];
  const float* Wk = (const float*)d_in[3];
  const float* bk = (const float*)d_in[4];
  const float* Wv = (const float*)d_in[5];
  const float* bv = (const float*)d_in[6];
  float* out = (float*)d_out;

  char* ws = (char*)d_ws;
  float*     sqp  = (float*)(ws + 0);                //  64 KB
  _Float16*  xh   = (_Float16*)(ws + 65536);         //   8 MB
  _Float16*  xl   = (_Float16*)(ws + 8454144);       //   8 MB
  float*     qf   = (float*)(ws + 16842752);         //  16 MB
  float*     kf   = (float*)(ws + 33619968);         //  16 MB
  float*     vf   = (float*)(ws + 50397184);         //  16 MB
  double*    pd   = (double*)(ws + 67174400);        //   8 MB
  int*       idxb = (int*)  (ws + 75563008);         //   1 MB
  _Float16*  whf  = (_Float16*)(ws + 76611584);      // 384 KB
  _Float16*  wlf  = (_Float16*)(ws + 77004800);      // 384 KB (total ~74 MB)

  k_prep  <<<4096, 256, 0, stream>>>(x, sqp, xh, xl);
  k_wsplit<<<768,  256, 0, stream>>>(Wq, Wk, Wv, whf, wlf);
  k_proj  <<<384,  256, 0, stream>>>(xh, xl, whf, wlf, bq, bk, bv, qf, kf, vf);
  k_knn   <<<512,  256, 0, stream>>>(xh, xl, sqp, pd);
  k_kmerge<<<64,   256, 0, stream>>>(pd, idxb);
  k_attn  <<<4096, 256, 0, stream>>>(qf, kf, vf, idxb, out);
}